// Round 1
// baseline (19422.984 us; speedup 1.0000x reference)
//
#include <hip/hip_runtime.h>
#include <math.h>

#define LSTM_L 200
#define LSTM_B 2048
#define LSTM_HIN 64
#define LSTM_H 256
#define LSTM_G 1024   // 4*H
#define NCLUST 64
#define HALF_BETA 0.05f

// ---------------------------------------------------------------------------
// Fused LSTM step: gates = xin @ Wih^T + hin @ Whh^T + (bih+bhh); then
// c = sig(f)*c + sig(i)*tanh(g); h = sig(o)*tanh(c).
// Block tile: 64 batch rows x 32 h-cols (x 4 gates = 128 gate cols). BK=32.
// 256 threads as (ty 0..15, tx 0..15); microtile 4 rows x (2 h-cols x 4 gates).
// ---------------------------------------------------------------------------
template<int KIN>
__global__ __launch_bounds__(256) void lstm_step_kernel(
    const float* __restrict__ xin,   // B x KIN
    const float* __restrict__ Wih,   // G x KIN (row-major)
    const float* __restrict__ Whh,   // G x H
    const float* __restrict__ bih,   // G
    const float* __restrict__ bhh,   // G
    const float* __restrict__ hin,   // B x H
    float* __restrict__ hout,        // B x H
    float* __restrict__ cst)         // B x H (in/out)
{
    constexpr int BM = 64, BNH = 32, BNG = 128, BK = 32;
    constexpr int KTOT = KIN + LSTM_H;
    // k-major LDS tiles; strides chosen: As stride 68 (16B-aligned reads,
    // 2-way-max write conflicts), Bs stride 130 (8B-aligned float2 reads).
    __shared__ float As[BK][BM + 4];
    __shared__ float Bs[BK][BNG + 2];

    const int tid = threadIdx.x;
    const int tx = tid & 15;
    const int ty = tid >> 4;
    const int b0 = blockIdx.x * BM;
    const int n0 = blockIdx.y * BNH;

    const int arow = tid >> 3;   // 0..31
    const int akq  = tid & 7;    // 0..7 (float4 index in a 32-float row chunk)

    float acc[4][8];
#pragma unroll
    for (int r = 0; r < 4; ++r)
#pragma unroll
        for (int c = 0; c < 8; ++c) acc[r][c] = 0.f;

    for (int k0 = 0; k0 < KTOT; k0 += BK) {
        const float* asrc; const float* bsrc; int aks, astr;
        if (k0 < KIN) { asrc = xin; bsrc = Wih; aks = k0;        astr = KIN; }
        else          { asrc = hin; bsrc = Whh; aks = k0 - KIN;  astr = LSTM_H; }

        // Stage A: 64 rows x 32 k (transposed into k-major LDS)
#pragma unroll
        for (int p = 0; p < 2; ++p) {
            int r = p * 32 + arow;
            const float4 v = *(const float4*)&asrc[(size_t)(b0 + r) * astr + aks + akq * 4];
            As[akq * 4 + 0][r] = v.x;
            As[akq * 4 + 1][r] = v.y;
            As[akq * 4 + 2][r] = v.z;
            As[akq * 4 + 3][r] = v.w;
        }
        // Stage B (weights): 128 gate rows x 32 k
#pragma unroll
        for (int p = 0; p < 4; ++p) {
            int cc = p * 32 + arow;                       // 0..127
            int j = n0 + (cc & 31) + ((cc >> 5) << 8);    // gate row in [0,1024)
            const float4 v = *(const float4*)&bsrc[(size_t)j * astr + aks + akq * 4];
            Bs[akq * 4 + 0][cc] = v.x;
            Bs[akq * 4 + 1][cc] = v.y;
            Bs[akq * 4 + 2][cc] = v.z;
            Bs[akq * 4 + 3][cc] = v.w;
        }
        __syncthreads();

#pragma unroll
        for (int k = 0; k < BK; ++k) {
            const float4 a = *(const float4*)&As[k][ty * 4];
            const float2 bg0 = *(const float2*)&Bs[k][0 * 32 + tx * 2];
            const float2 bg1 = *(const float2*)&Bs[k][1 * 32 + tx * 2];
            const float2 bg2 = *(const float2*)&Bs[k][2 * 32 + tx * 2];
            const float2 bg3 = *(const float2*)&Bs[k][3 * 32 + tx * 2];
            const float av[4] = {a.x, a.y, a.z, a.w};
            const float bv[8] = {bg0.x, bg0.y, bg1.x, bg1.y,
                                 bg2.x, bg2.y, bg3.x, bg3.y};
#pragma unroll
            for (int r = 0; r < 4; ++r)
#pragma unroll
                for (int c = 0; c < 8; ++c) acc[r][c] += av[r] * bv[c];
        }
        __syncthreads();
    }

    // Epilogue: bias + LSTM pointwise
#pragma unroll
    for (int u = 0; u < 2; ++u) {
        const int n = n0 + tx * 2 + u;
        const float bi = bih[n]       + bhh[n];
        const float bf = bih[n + 256] + bhh[n + 256];
        const float bg = bih[n + 512] + bhh[n + 512];
        const float bo = bih[n + 768] + bhh[n + 768];
#pragma unroll
        for (int rr = 0; rr < 4; ++rr) {
            const int row = b0 + ty * 4 + rr;
            const size_t idx = (size_t)row * LSTM_H + n;
            const float gi = acc[rr][0 + u] + bi;
            const float gf = acc[rr][2 + u] + bf;
            const float gg = acc[rr][4 + u] + bg;
            const float go = acc[rr][6 + u] + bo;
            const float si = 1.f / (1.f + expf(-gi));
            const float sf = 1.f / (1.f + expf(-gf));
            const float so = 1.f / (1.f + expf(-go));
            const float tg = tanhf(gg);
            const float cn = sf * cst[idx] + si * tg;
            cst[idx] = cn;
            hout[idx] = so * tanhf(cn);
        }
    }
}

// ---------------------------------------------------------------------------
// K-means assignment: one wave per sample; lane k = cluster k.
// ---------------------------------------------------------------------------
__global__ __launch_bounds__(64) void assign_kernel(
    const float* __restrict__ lat, const float* __restrict__ clusters,
    int* __restrict__ ids)
{
    __shared__ float row[LSTM_H];
    const int b = blockIdx.x;
    const int k = threadIdx.x;  // 0..63
    for (int i = k; i < LSTM_H; i += 64) row[i] = lat[(size_t)b * LSTM_H + i];
    __syncthreads();
    const float* ck = clusters + (size_t)k * LSTM_H;
    float d = 0.f;
#pragma unroll 8
    for (int i = 0; i < LSTM_H; ++i) { const float t = row[i] - ck[i]; d += t * t; }
    int idx = k;
    for (int off = 32; off > 0; off >>= 1) {
        const float od = __shfl_down(d, off, 64);
        const int   oi = __shfl_down(idx, off, 64);
        if (od < d || (od == d && oi < idx)) { d = od; idx = oi; }
    }
    if (k == 0) ids[b] = idx;
}

// ---------------------------------------------------------------------------
// Deterministic centroid update: block k scans all samples; thread = h column.
// ---------------------------------------------------------------------------
__global__ __launch_bounds__(256) void centroid_kernel(
    const float* __restrict__ lat, const int* __restrict__ ids,
    const float* __restrict__ clusters, float* __restrict__ upd)
{
    const int k = blockIdx.x;
    const int h = threadIdx.x;
    float s = 0.f;
    int cnt = 0;
    for (int b = 0; b < LSTM_B; ++b) {
        if (ids[b] == k) { s += lat[(size_t)b * LSTM_H + h]; cnt++; }
    }
    upd[(size_t)k * LSTM_H + h] =
        (cnt > 0) ? s / (float)cnt : clusters[(size_t)k * LSTM_H + h];
}

// ---------------------------------------------------------------------------
// Loss: 0.5*beta * sum ||lat - upd[id]||^2  -> atomicAdd into out_loss
// ---------------------------------------------------------------------------
__global__ __launch_bounds__(256) void loss_kernel(
    const float* __restrict__ lat, const int* __restrict__ ids,
    const float* __restrict__ upd, float* __restrict__ out_loss)
{
    float p = 0.f;
    const int total = LSTM_B * LSTM_H;
    for (int idx = blockIdx.x * blockDim.x + threadIdx.x; idx < total;
         idx += gridDim.x * blockDim.x) {
        const int b = idx >> 8;
        const float d = lat[idx] - upd[(size_t)ids[b] * LSTM_H + (idx & 255)];
        p += d * d;
    }
    for (int off = 32; off > 0; off >>= 1) p += __shfl_down(p, off, 64);
    __shared__ float wsum[4];
    const int lane = threadIdx.x & 63, wid = threadIdx.x >> 6;
    if (lane == 0) wsum[wid] = p;
    __syncthreads();
    if (threadIdx.x == 0) {
        atomicAdd(out_loss, HALF_BETA * (wsum[0] + wsum[1] + wsum[2] + wsum[3]));
    }
}

// ---------------------------------------------------------------------------
extern "C" void kernel_launch(void* const* d_in, const int* in_sizes, int n_in,
                              void* d_out, int out_size, void* d_ws, size_t ws_size,
                              hipStream_t stream)
{
    const float* X     = (const float*)d_in[0];
    const float* Wih0  = (const float*)d_in[1];
    const float* Whh0  = (const float*)d_in[2];
    const float* bih0  = (const float*)d_in[3];
    const float* bhh0  = (const float*)d_in[4];
    const float* Wih1  = (const float*)d_in[5];
    const float* Whh1  = (const float*)d_in[6];
    const float* bih1  = (const float*)d_in[7];
    const float* bhh1  = (const float*)d_in[8];
    const float* clust = (const float*)d_in[9];

    float* out = (float*)d_out;
    float* ws  = (float*)d_ws;

    const size_t BH = (size_t)LSTM_B * LSTM_H;   // 524288
    float* h0a = ws;
    float* h0b = ws + BH;
    float* h1a = ws + 2 * BH;
    float* h1b = ws + 3 * BH;
    float* c0  = ws + 4 * BH;
    float* c1  = ws + 5 * BH;
    float* upd = ws + 6 * BH;                     // 64*256
    int*   ids = (int*)(ws + 6 * BH + NCLUST * LSTM_H);  // 2048 ints

    // Zero initial states + loss slot (d_ws/d_out are poisoned, not re-zeroed)
    hipMemsetAsync(h0a, 0, BH * sizeof(float), stream);
    hipMemsetAsync(h1a, 0, BH * sizeof(float), stream);
    hipMemsetAsync(c0, 0, 2 * BH * sizeof(float), stream);  // c0 + c1 contiguous
    hipMemsetAsync(out + BH, 0, sizeof(float), stream);

    dim3 grid(LSTM_B / 64, LSTM_H / 32);  // 32 x 8
    dim3 blk(256);

    float* h0cur = h0a; float* h0nxt = h0b;
    float* h1cur = h1a; float* h1nxt = h1b;
    for (int t = 0; t < LSTM_L; ++t) {
        const float* xt = X + (size_t)t * LSTM_B * LSTM_HIN;
        lstm_step_kernel<LSTM_HIN><<<grid, blk, 0, stream>>>(
            xt, Wih0, Whh0, bih0, bhh0, h0cur, h0nxt, c0);
        float* h1dst = (t == LSTM_L - 1) ? out : h1nxt;
        lstm_step_kernel<LSTM_H><<<grid, blk, 0, stream>>>(
            h0nxt, Wih1, Whh1, bih1, bhh1, h1cur, h1dst, c1);
        float* tmp;
        tmp = h0cur; h0cur = h0nxt; h0nxt = tmp;
        tmp = h1cur; h1cur = h1nxt; h1nxt = tmp;
    }

    // k-means tail (latent lives in d_out[0 .. BH))
    assign_kernel<<<LSTM_B, 64, 0, stream>>>(out, clust, ids);
    centroid_kernel<<<NCLUST, 256, 0, stream>>>(out, ids, clust, upd);
    loss_kernel<<<256, 256, 0, stream>>>(out, ids, upd, out + BH);
}

// Round 2
// 3002.512 us; speedup vs baseline: 6.4689x; 6.4689x over previous
//
#include <hip/hip_runtime.h>
#include <hip/hip_bf16.h>
#include <math.h>

typedef unsigned short u16;
typedef __attribute__((ext_vector_type(8))) __bf16 bf16x8;
typedef __attribute__((ext_vector_type(4))) float f32x4;

#define LSTM_L 200
#define LSTM_B 2048
#define LSTM_HIN 64
#define LSTM_H 256
#define NCLUST 64
#define HALF_BETA 0.05f

__device__ __forceinline__ void gload_lds16(const void* g, void* l) {
    __builtin_amdgcn_global_load_lds(
        (__attribute__((address_space(1))) void*)g,
        (__attribute__((address_space(3))) void*)l, 16, 0, 0);
}

// ---------------------------------------------------------------------------
// Weight pack: Wcat[j][0:KIN] = Wih[j], Wcat[j][KIN:KIN+256] = Whh[j], bf16.
// j in [0,1024) gate-major (i,f,g,o blocks of 256 rows) as in torch layout.
// ---------------------------------------------------------------------------
template<int KIN>
__global__ __launch_bounds__(256) void pack_weights(
    const float* __restrict__ Wih, const float* __restrict__ Whh,
    u16* __restrict__ Wcat)
{
    constexpr int KTOT = KIN + LSTM_H;
    const int total = 1024 * KTOT;
    for (int i = blockIdx.x * 256 + threadIdx.x; i < total; i += gridDim.x * 256) {
        const int j = i / KTOT;
        const int k = i - j * KTOT;
        const float v = (k < KIN) ? Wih[(size_t)j * KIN + k]
                                  : Whh[(size_t)j * LSTM_H + (k - KIN)];
        const __bf16 b = (__bf16)v;
        Wcat[i] = __builtin_bit_cast(u16, b);
    }
}

// ---------------------------------------------------------------------------
// One LSTM layer step via MFMA. Block tile: 128 batch rows x 16 h-cols x 4
// gates. 4 waves split M (32 rows each); each wave: 2 M-frags x 4 gate-frags
// of mfma_f32_16x16x32_bf16. Gate g for element (m,n) sits in acc[fm][g][r]
// of the SAME lane -> register-local pointwise epilogue.
// A tile: [128][32] bf16 LDS (linear, slot = row*4 + k16). B tile: [64][32],
// row = gate*16 + within, from packed Wcat. BK=32 => every frag ds_read_b128
// covers a full contiguous 1KB LDS block => conflict-free, no swizzle.
// ---------------------------------------------------------------------------
template<int KIN, bool XF32>
__device__ __forceinline__ void run_layer(
    const void* __restrict__ xsrc,      // f32 X slice (XF32) or bf16 h0
    const u16* __restrict__ hin,        // bf16 hidden in
    const u16* __restrict__ Wcat,       // bf16 packed weights [1024][KIN+256]
    const float* __restrict__ bih, const float* __restrict__ bhh,
    u16* __restrict__ hout,             // bf16 hidden out
    float* __restrict__ latout,         // f32 latent out (or null)
    float* __restrict__ cst,            // f32 cell state (in/out)
    int blk, u16* As, u16* Bs, int tid)
{
    constexpr int KTOT = KIN + LSTM_H;
    constexpr int NCH = KTOT / 32;
    const int lane = tid & 63;
    const int w = tid >> 6;
    const int b0 = (blk & 15) * 128;
    const int n0 = (blk >> 4) * 16;

    f32x4 acc[2][4];
#pragma unroll
    for (int i = 0; i < 2; ++i)
#pragma unroll
        for (int j = 0; j < 4; ++j) acc[i][j] = f32x4{0.f, 0.f, 0.f, 0.f};

    for (int ch = 0; ch < NCH; ++ch) {
        const int k0 = ch * 32;
        // ---- stage A (128 rows x 32 k), 2 x 16B slots per thread ----
        if (XF32 && k0 < KIN) {
            const float* xs = (const float*)xsrc;
#pragma unroll
            for (int p = 0; p < 2; ++p) {
                const int slot = p * 256 + tid;
                const int row = slot >> 2;
                const int kk = (slot & 3) * 8;
                const float* s = xs + (size_t)(b0 + row) * KIN + k0 + kk;
                const float4 v0 = *(const float4*)s;
                const float4 v1 = *(const float4*)(s + 4);
                bf16x8 pk;
                pk[0] = (__bf16)v0.x; pk[1] = (__bf16)v0.y;
                pk[2] = (__bf16)v0.z; pk[3] = (__bf16)v0.w;
                pk[4] = (__bf16)v1.x; pk[5] = (__bf16)v1.y;
                pk[6] = (__bf16)v1.z; pk[7] = (__bf16)v1.w;
                *(bf16x8*)&As[slot * 8] = pk;
            }
        } else {
            const u16* src; int stride, kk;
            if (!XF32 && k0 < KIN) { src = (const u16*)xsrc; stride = KIN; kk = k0; }
            else                   { src = hin; stride = LSTM_H; kk = k0 - KIN; }
#pragma unroll
            for (int p = 0; p < 2; ++p) {
                const int slot = p * 256 + tid;   // wave-linear: base + lane
                const int row = slot >> 2;
                const int c16 = slot & 3;
                gload_lds16(src + (size_t)(b0 + row) * stride + kk + c16 * 8,
                            &As[slot * 8]);
            }
        }
        // ---- stage B (64 gate-rows x 32 k), 1 slot per thread ----
        {
            const int slot = tid;
            const int row = slot >> 2;
            const int c16 = slot & 3;
            const int j = (row >> 4) * 256 + n0 + (row & 15);
            gload_lds16(Wcat + (size_t)j * KTOT + k0 + c16 * 8, &Bs[slot * 8]);
        }
        __syncthreads();

        bf16x8 af[2], bf_[4];
#pragma unroll
        for (int fm = 0; fm < 2; ++fm)
            af[fm] = *(const bf16x8*)&As[(w * 32 + fm * 16 + (lane & 15)) * 32 +
                                         (lane >> 4) * 8];
#pragma unroll
        for (int fn = 0; fn < 4; ++fn)
            bf_[fn] = *(const bf16x8*)&Bs[(fn * 16 + (lane & 15)) * 32 +
                                          (lane >> 4) * 8];
#pragma unroll
        for (int fm = 0; fm < 2; ++fm)
#pragma unroll
            for (int fn = 0; fn < 4; ++fn)
                acc[fm][fn] = __builtin_amdgcn_mfma_f32_16x16x32_bf16(
                    af[fm], bf_[fn], acc[fm][fn], 0, 0, 0);
        __syncthreads();
    }

    // ---- epilogue: bias + LSTM pointwise, all register-local ----
    const int n = n0 + (lane & 15);
    const float bi = bih[n]       + bhh[n];
    const float bff = bih[n + 256] + bhh[n + 256];
    const float bg = bih[n + 512] + bhh[n + 512];
    const float bo = bih[n + 768] + bhh[n + 768];
#pragma unroll
    for (int fm = 0; fm < 2; ++fm) {
#pragma unroll
        for (int r = 0; r < 4; ++r) {
            const int m = b0 + w * 32 + fm * 16 + (lane >> 4) * 4 + r;
            const size_t idx = (size_t)m * LSTM_H + n;
            const float gi = acc[fm][0][r] + bi;
            const float gf = acc[fm][1][r] + bff;
            const float gg = acc[fm][2][r] + bg;
            const float go = acc[fm][3][r] + bo;
            const float si = 1.f / (1.f + expf(-gi));
            const float sf = 1.f / (1.f + expf(-gf));
            const float so = 1.f / (1.f + expf(-go));
            const float cn = sf * cst[idx] + si * tanhf(gg);
            cst[idx] = cn;
            const float hv = so * tanhf(cn);
            const __bf16 hb = (__bf16)hv;
            hout[idx] = __builtin_bit_cast(u16, hb);
            if (latout) latout[idx] = hv;
        }
    }
}

// Fused launch s: blocks 0-255 -> layer0 step s; blocks 256-511 -> layer1
// step s-1 (reads h0 written by the PREVIOUS launch -> no intra-launch dep).
__global__ __launch_bounds__(256) void lstm_step2(
    const float* __restrict__ xt,
    const u16* __restrict__ h0in, u16* __restrict__ h0out, float* __restrict__ c0,
    const u16* __restrict__ Wc0, const float* __restrict__ bih0, const float* __restrict__ bhh0,
    const u16* __restrict__ h1in, u16* __restrict__ h1out, float* __restrict__ c1,
    const u16* __restrict__ Wc1, const float* __restrict__ bih1, const float* __restrict__ bhh1,
    float* __restrict__ latout, int do0, int do1)
{
    __shared__ u16 As[128 * 32];
    __shared__ u16 Bs[64 * 32];
    const int tid = threadIdx.x;
    if (blockIdx.x < 256) {
        if (do0)
            run_layer<LSTM_HIN, true>(xt, h0in, Wc0, bih0, bhh0, h0out, nullptr,
                                      c0, blockIdx.x, As, Bs, tid);
    } else {
        if (do1)
            run_layer<LSTM_H, false>(h0in, h1in, Wc1, bih1, bhh1, h1out, latout,
                                     c1, blockIdx.x - 256, As, Bs, tid);
    }
}

// ---------------------------------------------------------------------------
// K-means tail (unchanged from fp32 baseline; operates on f32 latent in d_out)
// ---------------------------------------------------------------------------
__global__ __launch_bounds__(64) void assign_kernel(
    const float* __restrict__ lat, const float* __restrict__ clusters,
    int* __restrict__ ids)
{
    __shared__ float row[LSTM_H];
    const int b = blockIdx.x;
    const int k = threadIdx.x;
    for (int i = k; i < LSTM_H; i += 64) row[i] = lat[(size_t)b * LSTM_H + i];
    __syncthreads();
    const float* ck = clusters + (size_t)k * LSTM_H;
    float d = 0.f;
#pragma unroll 8
    for (int i = 0; i < LSTM_H; ++i) { const float t = row[i] - ck[i]; d += t * t; }
    int idx = k;
    for (int off = 32; off > 0; off >>= 1) {
        const float od = __shfl_down(d, off, 64);
        const int   oi = __shfl_down(idx, off, 64);
        if (od < d || (od == d && oi < idx)) { d = od; idx = oi; }
    }
    if (k == 0) ids[b] = idx;
}

__global__ __launch_bounds__(256) void centroid_kernel(
    const float* __restrict__ lat, const int* __restrict__ ids,
    const float* __restrict__ clusters, float* __restrict__ upd)
{
    const int k = blockIdx.x;
    const int h = threadIdx.x;
    float s = 0.f;
    int cnt = 0;
    for (int b = 0; b < LSTM_B; ++b) {
        if (ids[b] == k) { s += lat[(size_t)b * LSTM_H + h]; cnt++; }
    }
    upd[(size_t)k * LSTM_H + h] =
        (cnt > 0) ? s / (float)cnt : clusters[(size_t)k * LSTM_H + h];
}

__global__ __launch_bounds__(256) void loss_kernel(
    const float* __restrict__ lat, const int* __restrict__ ids,
    const float* __restrict__ upd, float* __restrict__ out_loss)
{
    float p = 0.f;
    const int total = LSTM_B * LSTM_H;
    for (int idx = blockIdx.x * blockDim.x + threadIdx.x; idx < total;
         idx += gridDim.x * blockDim.x) {
        const int b = idx >> 8;
        const float d = lat[idx] - upd[(size_t)ids[b] * LSTM_H + (idx & 255)];
        p += d * d;
    }
    for (int off = 32; off > 0; off >>= 1) p += __shfl_down(p, off, 64);
    __shared__ float wsum[4];
    const int lane = threadIdx.x & 63, wid = threadIdx.x >> 6;
    if (lane == 0) wsum[wid] = p;
    __syncthreads();
    if (threadIdx.x == 0)
        atomicAdd(out_loss, HALF_BETA * (wsum[0] + wsum[1] + wsum[2] + wsum[3]));
}

// ---------------------------------------------------------------------------
extern "C" void kernel_launch(void* const* d_in, const int* in_sizes, int n_in,
                              void* d_out, int out_size, void* d_ws, size_t ws_size,
                              hipStream_t stream)
{
    const float* X     = (const float*)d_in[0];
    const float* Wih0  = (const float*)d_in[1];
    const float* Whh0  = (const float*)d_in[2];
    const float* bih0  = (const float*)d_in[3];
    const float* bhh0  = (const float*)d_in[4];
    const float* Wih1  = (const float*)d_in[5];
    const float* Whh1  = (const float*)d_in[6];
    const float* bih1  = (const float*)d_in[7];
    const float* bhh1  = (const float*)d_in[8];
    const float* clust = (const float*)d_in[9];

    float* out = (float*)d_out;
    char* base = (char*)d_ws;

    const size_t MB = 1u << 20;
    float* c0  = (float*)(base + 0 * MB);    // 2 MB
    float* c1  = (float*)(base + 2 * MB);    // 2 MB
    u16* h0a   = (u16*)(base + 4 * MB);      // 1 MB each
    u16* h0b   = (u16*)(base + 5 * MB);
    u16* h1a   = (u16*)(base + 6 * MB);
    u16* h1b   = (u16*)(base + 7 * MB);
    u16* Wc0   = (u16*)(base + 8 * MB);      // 640 KB
    u16* Wc1   = (u16*)(base + 9 * MB);      // 1 MB
    float* upd = (float*)(base + 10 * MB);   // 64 KB
    int* ids   = (int*)(base + 10 * MB + 256 * 1024);  // 8 KB

    const size_t BH = (size_t)LSTM_B * LSTM_H;

    // zero: cell states, initial hiddens, loss slot
    hipMemsetAsync(c0, 0, 4 * MB, stream);          // c0 + c1 contiguous
    hipMemsetAsync(h0a, 0, MB, stream);
    hipMemsetAsync(h1a, 0, MB, stream);
    hipMemsetAsync(out + BH, 0, sizeof(float), stream);

    pack_weights<LSTM_HIN><<<320, 256, 0, stream>>>(Wih0, Whh0, Wc0);
    pack_weights<LSTM_H>  <<<512, 256, 0, stream>>>(Wih1, Whh1, Wc1);

    u16* h0cur = h0a; u16* h0nxt = h0b;
    u16* h1cur = h1a; u16* h1nxt = h1b;
    for (int s = 0; s <= LSTM_L; ++s) {
        const int do0 = (s < LSTM_L) ? 1 : 0;
        const int do1 = (s > 0) ? 1 : 0;
        const float* xt = do0 ? X + (size_t)s * LSTM_B * LSTM_HIN : nullptr;
        float* lat = (s == LSTM_L) ? out : nullptr;
        lstm_step2<<<512, 256, 0, stream>>>(
            xt, h0cur, h0nxt, c0, Wc0, bih0, bhh0,
            h1cur, h1nxt, c1, Wc1, bih1, bhh1, lat, do0, do1);
        if (do0) { u16* t = h0cur; h0cur = h0nxt; h0nxt = t; }
        if (do1) { u16* t = h1cur; h1cur = h1nxt; h1nxt = t; }
    }

    assign_kernel<<<LSTM_B, 64, 0, stream>>>(out, clust, ids);
    centroid_kernel<<<NCLUST, 256, 0, stream>>>(out, ids, clust, upd);
    loss_kernel<<<256, 256, 0, stream>>>(out, ids, upd, out + BH);
}